// Round 9
// baseline (368.058 us; speedup 1.0000x reference)
//
#include <hip/hip_runtime.h>
#include <math.h>

#define LL 2048
#define DD 128
#define NS 16                          // 2 sources * 8 batches
#define SLAB (LL * DD)                 // 262144 elements per (src,n)
#define SCALE 0.08838834764831845f     // 1/sqrt(128)
#define NT 16                          // 128-row tiles per slab
#define NPAIR 136                      // NT*(NT+1)/2 upper-triangle pairs
#define LSTR 40                        // LDS row stride in bf16 (32 + 8 pad)

typedef __attribute__((ext_vector_type(8))) short short8v;   // 8 bf16 (4 VGPR)
typedef __attribute__((ext_vector_type(4))) float float4v;   // MFMA C/D

__device__ __forceinline__ unsigned int f2bf(float f) {   // RNE, low 16 bits
    unsigned int u = __float_as_uint(f);
    u += 0x7fffu + ((u >> 16) & 1u);
    return u >> 16;
}
__device__ __forceinline__ void pair_decode(int p, int& ib, int& jb) {
    int i = 0;
    while (p >= NT - i) { p -= NT - i; ++i; }
    ib = i; jb = i + p;
}

// ---------------------------------------------------------------------------
// Kernel 1: P = x @ W^T + b (fp32), split to P_hi/P_lo bf16 in d_out.
// Block: 64 l-rows x 128 d. Grid: (32 l-tiles, 16 ns) = 512 blocks.
// ---------------------------------------------------------------------------
__global__ __launch_bounds__(256, 4) void proj_kernel(
    const float* __restrict__ xt, const float* __restrict__ xf,
    const float* __restrict__ W,  const float* __restrict__ bias,
    unsigned short* __restrict__ Ph, unsigned short* __restrict__ Pl)
{
    __shared__ float Alds[64 * 36];
    __shared__ float Blds[128 * 36];
    __shared__ float bs[128];
    const int ns = blockIdx.y;
    const int l0 = blockIdx.x * 64;
    const int src = ns >> 3, n = ns & 7;
    const float* x = (src ? xf : xt) + (size_t)n * LL * DD;
    const int tid = threadIdx.x;
    const int ty = tid >> 4, tx = tid & 15;

    if (tid < 128) bs[tid] = bias[tid];
    __syncthreads();

    float acc[4][8];
#pragma unroll
    for (int i = 0; i < 4; ++i)
#pragma unroll
        for (int j = 0; j < 8; ++j) acc[i][j] = bs[tx + 16 * j];

    for (int kc = 0; kc < 4; ++kc) {
        __syncthreads();
#pragma unroll
        for (int t = 0; t < 2; ++t) {            // x: 64 x 32 = 512 float4
            int idx = tid + t * 256;
            int r = idx >> 3, k4 = (idx & 7) << 2;
            *(float4*)&Alds[r * 36 + k4] =
                *(const float4*)&x[(size_t)(l0 + r) * DD + kc * 32 + k4];
        }
#pragma unroll
        for (int t = 0; t < 4; ++t) {            // W: 128 x 32 = 1024 float4
            int idx = tid + t * 256;
            int r = idx >> 3, k4 = (idx & 7) << 2;
            *(float4*)&Blds[r * 36 + k4] =
                *(const float4*)&W[(size_t)r * DD + kc * 32 + k4];
        }
        __syncthreads();
#pragma unroll
        for (int k4 = 0; k4 < 32; k4 += 4) {
            float4 a4[4], b4[8];
#pragma unroll
            for (int i = 0; i < 4; ++i) a4[i] = *(const float4*)&Alds[(ty + 16 * i) * 36 + k4];
#pragma unroll
            for (int j = 0; j < 8; ++j) b4[j] = *(const float4*)&Blds[(tx + 16 * j) * 36 + k4];
#pragma unroll
            for (int i = 0; i < 4; ++i)
#pragma unroll
                for (int j = 0; j < 8; ++j) {
                    acc[i][j] = fmaf(a4[i].x, b4[j].x, acc[i][j]);
                    acc[i][j] = fmaf(a4[i].y, b4[j].y, acc[i][j]);
                    acc[i][j] = fmaf(a4[i].z, b4[j].z, acc[i][j]);
                    acc[i][j] = fmaf(a4[i].w, b4[j].w, acc[i][j]);
                }
        }
    }
#pragma unroll
    for (int i = 0; i < 4; ++i) {
        const size_t rowo = (size_t)ns * SLAB + (size_t)(l0 + ty + 16 * i) * DD;
#pragma unroll
        for (int j = 0; j < 8; ++j) {
            float p = acc[i][j];
            unsigned int hb = f2bf(p);
            float hf = __uint_as_float(hb << 16);
            unsigned int lb = f2bf(p - hf);
            Ph[rowo + tx + 16 * j] = (unsigned short)hb;
            Pl[rowo + tx + 16 * j] = (unsigned short)lb;
        }
    }
}

// ---------------------------------------------------------------------------
// MFMA bf16x3 GEMM core (hi*hi + hi*lo + lo*hi): wave computes 32x128 of the
// 128x128 tile S(ib,jb). acc frag: col = lane&15, row = quad*4 + reg.
// ---------------------------------------------------------------------------
__device__ __forceinline__ void mfma_core(
    const unsigned short* __restrict__ Ph, const unsigned short* __restrict__ Pl,
    int ns, int ib, int jb, int tid,
    unsigned short* Ah, unsigned short* Alo, unsigned short* Bh, unsigned short* Blo,
    float4v acc[2][8])
{
    const int lane = tid & 63;
    const int quad = lane >> 4, l16 = lane & 15;
    const int wave = tid >> 6;
    const int arow = wave * 32;
    const unsigned short* sAh = Ph + (size_t)ns * SLAB + (size_t)ib * 128 * DD;
    const unsigned short* sAl = Pl + (size_t)ns * SLAB + (size_t)ib * 128 * DD;
    const unsigned short* sBh = Ph + (size_t)ns * SLAB + (size_t)jb * 128 * DD;
    const unsigned short* sBl = Pl + (size_t)ns * SLAB + (size_t)jb * 128 * DD;

#pragma unroll
    for (int rt = 0; rt < 2; ++rt)
#pragma unroll
        for (int ct = 0; ct < 8; ++ct)
#pragma unroll
            for (int r = 0; r < 4; ++r) acc[rt][ct][r] = 0.f;

    for (int kc = 0; kc < 4; ++kc) {
        __syncthreads();
#pragma unroll
        for (int it = 0; it < 2; ++it) {
            int idx = tid + it * 256;          // 512 16B-chunks per array
            int r = idx >> 2, c4 = idx & 3;
            size_t go = (size_t)r * DD + kc * 32 + c4 * 8;
            int lo = r * LSTR + c4 * 8;
            *(uint4*)&Ah[lo]  = *(const uint4*)&sAh[go];
            *(uint4*)&Alo[lo] = *(const uint4*)&sAl[go];
            *(uint4*)&Bh[lo]  = *(const uint4*)&sBh[go];
            *(uint4*)&Blo[lo] = *(const uint4*)&sBl[go];
        }
        __syncthreads();
        const int kb = quad * 8;               // A: m=lane&15, k=quad*8+j
        short8v bh[8], bl[8];
#pragma unroll
        for (int ct = 0; ct < 8; ++ct) {
            int ba = (ct * 16 + l16) * LSTR + kb;
            bh[ct] = *(const short8v*)&Bh[ba];
            bl[ct] = *(const short8v*)&Blo[ba];
        }
#pragma unroll
        for (int rt = 0; rt < 2; ++rt) {
            int aa = (arow + rt * 16 + l16) * LSTR + kb;
            short8v ah = *(const short8v*)&Ah[aa];
            short8v al = *(const short8v*)&Alo[aa];
#pragma unroll
            for (int ct = 0; ct < 8; ++ct) {
                acc[rt][ct] = __builtin_amdgcn_mfma_f32_16x16x32_bf16(ah, bh[ct], acc[rt][ct], 0, 0, 0);
                acc[rt][ct] = __builtin_amdgcn_mfma_f32_16x16x32_bf16(ah, bl[ct], acc[rt][ct], 0, 0, 0);
                acc[rt][ct] = __builtin_amdgcn_mfma_f32_16x16x32_bf16(al, bh[ct], acc[rt][ct], 0, 0, 0);
            }
        }
    }
}

// ---------------------------------------------------------------------------
// Kernel 2: per tile-pair UNSHIFTED softmax denominators: Zpart row sums of
// exp(s) for rows of BOTH blocks. Zpart: [(ns*16 + othertile)*2048 + row]
// ---------------------------------------------------------------------------
__global__ __launch_bounds__(256, 4) void stats_kernel(
    const unsigned short* __restrict__ Ph, const unsigned short* __restrict__ Pl,
    float* __restrict__ Zpart)
{
    __shared__ unsigned int AhU[2560], AlU[2560], BhU[2560], BlU[2560];  // 40 KB
    int ib, jb;  pair_decode(blockIdx.x, ib, jb);
    const int ns = blockIdx.y;
    const int tid = threadIdx.x;
    const int lane = tid & 63, quad = lane >> 4, l16 = lane & 15, wave = tid >> 6;
    const int arow = wave * 32;

    float4v acc[2][8];
    mfma_core(Ph, Pl, ns, ib, jb, tid,
              (unsigned short*)AhU, (unsigned short*)AlU,
              (unsigned short*)BhU, (unsigned short*)BlU, acc);

    float cs[8];
#pragma unroll
    for (int ct = 0; ct < 8; ++ct) cs[ct] = 0.f;

#pragma unroll
    for (int rt = 0; rt < 2; ++rt)
#pragma unroll
        for (int rg = 0; rg < 4; ++rg) {
            float e[8];
#pragma unroll
            for (int ct = 0; ct < 8; ++ct) e[ct] = __expf(acc[rt][ct][rg] * SCALE);
            float s = 0.f;
#pragma unroll
            for (int ct = 0; ct < 8; ++ct) { s += e[ct]; cs[ct] += e[ct]; }
            s += __shfl_xor(s, 1);
            s += __shfl_xor(s, 2);
            s += __shfl_xor(s, 4);
            s += __shfl_xor(s, 8);
            if (l16 == 0) {
                int o = (ns * 16 + jb) * LL + ib * 128 + arow + rt * 16 + quad * 4 + rg;
                Zpart[o] = s;
            }
        }

    // transpose: row sums for rows of jb (= cols here) over 128 rows of ib
    if (ib != jb) {
#pragma unroll
        for (int ct = 0; ct < 8; ++ct) {
            float s = cs[ct];
            s += __shfl_xor(s, 16);
            s += __shfl_xor(s, 32);
            cs[ct] = s;
        }
        __syncthreads();
        float* scs = (float*)AhU;                          // [128][5]
        if (quad == 0) {
#pragma unroll
            for (int ct = 0; ct < 8; ++ct) scs[(ct * 16 + l16) * 5 + wave] = cs[ct];
        }
        __syncthreads();
        if (tid < 128) {
            float S = scs[tid * 5] + scs[tid * 5 + 1] + scs[tid * 5 + 2] + scs[tid * 5 + 3];
            Zpart[(ns * 16 + ib) * LL + jb * 128 + tid] = S;
        }
    }
}

// ---------------------------------------------------------------------------
// Kernel 3: iZ[row] = 1 / sum of 16 per-tile partials
// ---------------------------------------------------------------------------
__global__ __launch_bounds__(256) void reduce_stats_kernel(
    const float* __restrict__ Zpart, float* __restrict__ iZfin)
{
    const int idx = blockIdx.x * 256 + threadIdx.x;   // ns*2048 + l
    const int ns = idx >> 11, l = idx & 2047;
    float Z = 0.f;
#pragma unroll
    for (int t = 0; t < 16; ++t) Z += Zpart[(ns * 16 + t) * LL + l];
    iZfin[idx] = 1.0f / Z;
}

// ---------------------------------------------------------------------------
// Kernel 4: recompute s (identical MFMA sequence), per-tile column partial
// sums of exp(s)*iZ_row for cols of BOTH blocks. Spart: [(ns*2048+m)*16+tile]
// ---------------------------------------------------------------------------
__global__ __launch_bounds__(256, 4) void colsum_kernel(
    const unsigned short* __restrict__ Ph, const unsigned short* __restrict__ Pl,
    const float* __restrict__ iZfin, float* __restrict__ Spart)
{
    __shared__ unsigned int AhU[2560], AlU[2560], BhU[2560], BlU[2560];
    int ib, jb;  pair_decode(blockIdx.x, ib, jb);
    const int ns = blockIdx.y;
    const int tid = threadIdx.x;
    const int lane = tid & 63, quad = lane >> 4, l16 = lane & 15, wave = tid >> 6;
    const int arow = wave * 32;

    float4v acc[2][8];
    mfma_core(Ph, Pl, ns, ib, jb, tid,
              (unsigned short*)AhU, (unsigned short*)AlU,
              (unsigned short*)BhU, (unsigned short*)BlU, acc);

    float wrow[2][4];
#pragma unroll
    for (int rt = 0; rt < 2; ++rt)
#pragma unroll
        for (int rg = 0; rg < 4; ++rg)
            wrow[rt][rg] = iZfin[ns * LL + ib * 128 + arow + rt * 16 + quad * 4 + rg];
    float wcol[8];
#pragma unroll
    for (int ct = 0; ct < 8; ++ct)
        wcol[ct] = iZfin[ns * LL + jb * 128 + ct * 16 + l16];

    float dsum[8];
#pragma unroll
    for (int ct = 0; ct < 8; ++ct) dsum[ct] = 0.f;

#pragma unroll
    for (int rt = 0; rt < 2; ++rt)
#pragma unroll
        for (int rg = 0; rg < 4; ++rg) {
            const int rl = arow + rt * 16 + quad * 4 + rg;
            float ts = 0.f;
#pragma unroll
            for (int ct = 0; ct < 8; ++ct) {
                float e = __expf(acc[rt][ct][rg] * SCALE);
                bool diag = (ib == jb) && (rl == ct * 16 + l16);
                dsum[ct] += diag ? 0.f : e * wrow[rt][rg];
                ts += e * wcol[ct];
            }
            if (ib != jb) {
                ts += __shfl_xor(ts, 1);
                ts += __shfl_xor(ts, 2);
                ts += __shfl_xor(ts, 4);
                ts += __shfl_xor(ts, 8);
                if (l16 == 0)
                    Spart[((size_t)ns * LL + ib * 128 + rl) * 16 + jb] = ts;
            }
        }

#pragma unroll
    for (int ct = 0; ct < 8; ++ct) {
        float s = dsum[ct];
        s += __shfl_xor(s, 16);
        s += __shfl_xor(s, 32);
        dsum[ct] = s;
    }
    __syncthreads();
    float* scr = (float*)AhU;                 // [128][5] cross-wave combine
    if (quad == 0) {
#pragma unroll
        for (int ct = 0; ct < 8; ++ct) scr[(ct * 16 + l16) * 5 + wave] = dsum[ct];
    }
    __syncthreads();
    if (tid < 128) {
        float t = scr[tid * 5] + scr[tid * 5 + 1] + scr[tid * 5 + 2] + scr[tid * 5 + 3];
        Spart[((size_t)ns * LL + jb * 128 + tid) * 16 + ib] = t;
    }
}

// ---------------------------------------------------------------------------
// Kernel 5: score = fp64 sum of 16 tile partials; exact bottom-k mask via
// rank counting: mask[i] = #{j: score_j < score_i} < 1024
// ---------------------------------------------------------------------------
__global__ __launch_bounds__(1024) void mask_kernel(
    const float* __restrict__ Spart, unsigned char* __restrict__ maskbuf)
{
    __shared__ double s[LL];
    const int ns = blockIdx.x;
    const int half = blockIdx.y;
    const int tid = threadIdx.x;
#pragma unroll
    for (int h = 0; h < 2; ++h) {
        int m = tid + h * 1024;
        const float* sp = Spart + ((size_t)ns * LL + m) * 16;
        double a = 0.0;
#pragma unroll
        for (int t = 0; t < 16; ++t) a += (double)sp[t];
        s[m] = a;
    }
    __syncthreads();
    const int i = half * 1024 + tid;
    const double si = s[i];
    int cnt = 0;
    for (int j = 0; j < LL; ++j) cnt += (s[j] < si) ? 1 : 0;
    maskbuf[ns * LL + i] = (cnt < 1024) ? 1 : 0;
}

// ---------------------------------------------------------------------------
// Kernel 6: blend, all fp32.
// ---------------------------------------------------------------------------
__global__ __launch_bounds__(256) void blend_kernel(
    const float* __restrict__ xt, const float* __restrict__ xf,
    const unsigned char* __restrict__ maskbuf, float* __restrict__ out)
{
    const int idx4 = blockIdx.x * 256 + threadIdx.x;
    const size_t q = (size_t)idx4 * 4;
    const int row = (int)(q >> 7);
    const float4 a = *(const float4*)(xt + q);
    const float4 b = *(const float4*)(xf + q);
    const int mt = maskbuf[row] & 1;
    const int mf = maskbuf[16384 + row] & 1;
    const bool ct = mt && !mf;
    const bool cf = mf && !mt;
    float4 av;
    av.x = 0.5f * (a.x + b.x);  av.y = 0.5f * (a.y + b.y);
    av.z = 0.5f * (a.z + b.z);  av.w = 0.5f * (a.w + b.w);
    float4 o0 = ct ? av : a;
    float4 o1 = cf ? av : b;
    *(float4*)(out + q)                   = o0;
    *(float4*)(out + (size_t)2097152 + q) = o1;
}

// ---------------------------------------------------------------------------
extern "C" void kernel_launch(void* const* d_in, const int* in_sizes, int n_in,
                              void* d_out, int out_size, void* d_ws, size_t ws_size,
                              hipStream_t stream)
{
    const float* xt = (const float*)d_in[0];
    const float* xf = (const float*)d_in[1];
    const float* W  = (const float*)d_in[2];
    const float* b  = (const float*)d_in[3];
    float* out = (float*)d_out;

    // d_out (16.8 MB) holds P split: Ph bf16 [0,8.39MB), Pl bf16 [8.39,16.8MB).
    // Both dead before blend overwrites d_out.
    unsigned short* Ph = (unsigned short*)d_out;
    unsigned short* Pl = Ph + (size_t)NS * SLAB;

    float* Zpart = (float*)d_ws;                       // 16*16*2048 = 524288 f
    float* iZfin = Zpart + 16 * 16 * LL;               // 32768 f
    float* Spart = iZfin + NS * LL;                    // 524288 f
    unsigned char* maskbuf = (unsigned char*)(Spart + (size_t)16 * LL * 16);
    // total ws ~4.4 MB

    proj_kernel<<<dim3(32, NS), 256, 0, stream>>>(xt, xf, W, b, Ph, Pl);
    stats_kernel<<<dim3(NPAIR, NS), 256, 0, stream>>>(Ph, Pl, Zpart);
    reduce_stats_kernel<<<128, 256, 0, stream>>>(Zpart, iZfin);
    colsum_kernel<<<dim3(NPAIR, NS), 256, 0, stream>>>(Ph, Pl, iZfin, Spart);
    mask_kernel<<<dim3(NS, 2), 1024, 0, stream>>>(Spart, maskbuf);
    blend_kernel<<<2048, 256, 0, stream>>>(xt, xf, maskbuf, out);
}

// Round 10
// 221.772 us; speedup vs baseline: 1.6596x; 1.6596x over previous
//
#include <hip/hip_runtime.h>
#include <math.h>

#define LL 2048
#define DD 128
#define NS 16                          // 2 sources * 8 batches
#define SLAB (LL * DD)                 // 262144 elements per (src,n)
#define SCALE 0.08838834764831845f     // 1/sqrt(128)
#define NT 16                          // 128-row tiles per slab
#define NPAIR 136                      // NT*(NT+1)/2 upper-triangle pairs
#define LSTR 40                        // LDS row stride in bf16 (32 + 8 pad)

typedef __attribute__((ext_vector_type(8))) short short8v;   // 8 bf16 (4 VGPR)
typedef __attribute__((ext_vector_type(4))) float float4v;   // MFMA C/D

__device__ __forceinline__ unsigned int f2bf(float f) {   // RNE, low 16 bits
    unsigned int u = __float_as_uint(f);
    u += 0x7fffu + ((u >> 16) & 1u);
    return u >> 16;
}
__device__ __forceinline__ void pair_decode(int p, int& ib, int& jb) {
    int i = 0;
    while (p >= NT - i) { p -= NT - i; ++i; }
    ib = i; jb = i + p;
}

// ---------------------------------------------------------------------------
// Kernel 1: P = x @ W^T + b (fp32), split to P_hi/P_lo bf16 in d_out.
// Block: 64 l-rows x 128 d. Grid: (32 l-tiles, 16 ns) = 512 blocks.
// ---------------------------------------------------------------------------
__global__ __launch_bounds__(256, 4) void proj_kernel(
    const float* __restrict__ xt, const float* __restrict__ xf,
    const float* __restrict__ W,  const float* __restrict__ bias,
    unsigned short* __restrict__ Ph, unsigned short* __restrict__ Pl)
{
    __shared__ float Alds[64 * 36];
    __shared__ float Blds[128 * 36];
    __shared__ float bs[128];
    const int ns = blockIdx.y;
    const int l0 = blockIdx.x * 64;
    const int src = ns >> 3, n = ns & 7;
    const float* x = (src ? xf : xt) + (size_t)n * LL * DD;
    const int tid = threadIdx.x;
    const int ty = tid >> 4, tx = tid & 15;

    if (tid < 128) bs[tid] = bias[tid];
    __syncthreads();

    float acc[4][8];
#pragma unroll
    for (int i = 0; i < 4; ++i)
#pragma unroll
        for (int j = 0; j < 8; ++j) acc[i][j] = bs[tx + 16 * j];

    for (int kc = 0; kc < 4; ++kc) {
        __syncthreads();
#pragma unroll
        for (int t = 0; t < 2; ++t) {            // x: 64 x 32 = 512 float4
            int idx = tid + t * 256;
            int r = idx >> 3, k4 = (idx & 7) << 2;
            *(float4*)&Alds[r * 36 + k4] =
                *(const float4*)&x[(size_t)(l0 + r) * DD + kc * 32 + k4];
        }
#pragma unroll
        for (int t = 0; t < 4; ++t) {            // W: 128 x 32 = 1024 float4
            int idx = tid + t * 256;
            int r = idx >> 3, k4 = (idx & 7) << 2;
            *(float4*)&Blds[r * 36 + k4] =
                *(const float4*)&W[(size_t)r * DD + kc * 32 + k4];
        }
        __syncthreads();
#pragma unroll
        for (int k4 = 0; k4 < 32; k4 += 4) {
            float4 a4[4], b4[8];
#pragma unroll
            for (int i = 0; i < 4; ++i) a4[i] = *(const float4*)&Alds[(ty + 16 * i) * 36 + k4];
#pragma unroll
            for (int j = 0; j < 8; ++j) b4[j] = *(const float4*)&Blds[(tx + 16 * j) * 36 + k4];
#pragma unroll
            for (int i = 0; i < 4; ++i)
#pragma unroll
                for (int j = 0; j < 8; ++j) {
                    acc[i][j] = fmaf(a4[i].x, b4[j].x, acc[i][j]);
                    acc[i][j] = fmaf(a4[i].y, b4[j].y, acc[i][j]);
                    acc[i][j] = fmaf(a4[i].z, b4[j].z, acc[i][j]);
                    acc[i][j] = fmaf(a4[i].w, b4[j].w, acc[i][j]);
                }
        }
    }
#pragma unroll
    for (int i = 0; i < 4; ++i) {
        const size_t rowo = (size_t)ns * SLAB + (size_t)(l0 + ty + 16 * i) * DD;
#pragma unroll
        for (int j = 0; j < 8; ++j) {
            float p = acc[i][j];
            unsigned int hb = f2bf(p);
            float hf = __uint_as_float(hb << 16);
            unsigned int lb = f2bf(p - hf);
            Ph[rowo + tx + 16 * j] = (unsigned short)hb;
            Pl[rowo + tx + 16 * j] = (unsigned short)lb;
        }
    }
}

// ---------------------------------------------------------------------------
// MFMA bf16x3 GEMM core (hi*hi + hi*lo + lo*hi): wave computes 32x128 of the
// 128x128 tile S(ib,jb). acc frag: col = lane&15, row = quad*4 + reg.
// ---------------------------------------------------------------------------
__device__ __forceinline__ void mfma_core(
    const unsigned short* __restrict__ Ph, const unsigned short* __restrict__ Pl,
    int ns, int ib, int jb, int tid,
    unsigned short* Ah, unsigned short* Alo, unsigned short* Bh, unsigned short* Blo,
    float4v acc[2][8])
{
    const int lane = tid & 63;
    const int quad = lane >> 4, l16 = lane & 15;
    const int wave = tid >> 6;
    const int arow = wave * 32;
    const unsigned short* sAh = Ph + (size_t)ns * SLAB + (size_t)ib * 128 * DD;
    const unsigned short* sAl = Pl + (size_t)ns * SLAB + (size_t)ib * 128 * DD;
    const unsigned short* sBh = Ph + (size_t)ns * SLAB + (size_t)jb * 128 * DD;
    const unsigned short* sBl = Pl + (size_t)ns * SLAB + (size_t)jb * 128 * DD;

#pragma unroll
    for (int rt = 0; rt < 2; ++rt)
#pragma unroll
        for (int ct = 0; ct < 8; ++ct)
#pragma unroll
            for (int r = 0; r < 4; ++r) acc[rt][ct][r] = 0.f;

    for (int kc = 0; kc < 4; ++kc) {
        __syncthreads();
#pragma unroll
        for (int it = 0; it < 2; ++it) {
            int idx = tid + it * 256;          // 512 16B-chunks per array
            int r = idx >> 2, c4 = idx & 3;
            size_t go = (size_t)r * DD + kc * 32 + c4 * 8;
            int lo = r * LSTR + c4 * 8;
            *(uint4*)&Ah[lo]  = *(const uint4*)&sAh[go];
            *(uint4*)&Alo[lo] = *(const uint4*)&sAl[go];
            *(uint4*)&Bh[lo]  = *(const uint4*)&sBh[go];
            *(uint4*)&Blo[lo] = *(const uint4*)&sBl[go];
        }
        __syncthreads();
        const int kb = quad * 8;               // A: m=lane&15, k=quad*8+j
        short8v bh[8], bl[8];
#pragma unroll
        for (int ct = 0; ct < 8; ++ct) {
            int ba = (ct * 16 + l16) * LSTR + kb;
            bh[ct] = *(const short8v*)&Bh[ba];
            bl[ct] = *(const short8v*)&Blo[ba];
        }
#pragma unroll
        for (int rt = 0; rt < 2; ++rt) {
            int aa = (arow + rt * 16 + l16) * LSTR + kb;
            short8v ah = *(const short8v*)&Ah[aa];
            short8v al = *(const short8v*)&Alo[aa];
#pragma unroll
            for (int ct = 0; ct < 8; ++ct) {
                acc[rt][ct] = __builtin_amdgcn_mfma_f32_16x16x32_bf16(ah, bh[ct], acc[rt][ct], 0, 0, 0);
                acc[rt][ct] = __builtin_amdgcn_mfma_f32_16x16x32_bf16(ah, bl[ct], acc[rt][ct], 0, 0, 0);
                acc[rt][ct] = __builtin_amdgcn_mfma_f32_16x16x32_bf16(al, bh[ct], acc[rt][ct], 0, 0, 0);
            }
        }
    }
}

// ---------------------------------------------------------------------------
// Kernel 2: per tile-pair UNSHIFTED softmax denominators: Zpart row sums of
// exp(s) for rows of BOTH blocks. Zpart: [(ns*16 + othertile)*2048 + row]
// launch_bounds (256,3): 3 blocks/CU -> no VGPR spill (R9 lesson: 4 spilled)
// ---------------------------------------------------------------------------
__global__ __launch_bounds__(256, 3) void stats_kernel(
    const unsigned short* __restrict__ Ph, const unsigned short* __restrict__ Pl,
    float* __restrict__ Zpart)
{
    __shared__ unsigned int AhU[2560], AlU[2560], BhU[2560], BlU[2560];  // 40 KB
    int ib, jb;  pair_decode(blockIdx.x, ib, jb);
    const int ns = blockIdx.y;
    const int tid = threadIdx.x;
    const int lane = tid & 63, quad = lane >> 4, l16 = lane & 15, wave = tid >> 6;
    const int arow = wave * 32;

    float4v acc[2][8];
    mfma_core(Ph, Pl, ns, ib, jb, tid,
              (unsigned short*)AhU, (unsigned short*)AlU,
              (unsigned short*)BhU, (unsigned short*)BlU, acc);

    float cs[8];
#pragma unroll
    for (int ct = 0; ct < 8; ++ct) cs[ct] = 0.f;

#pragma unroll
    for (int rt = 0; rt < 2; ++rt)
#pragma unroll
        for (int rg = 0; rg < 4; ++rg) {
            float e[8];
#pragma unroll
            for (int ct = 0; ct < 8; ++ct) e[ct] = __expf(acc[rt][ct][rg] * SCALE);
            float s = 0.f;
#pragma unroll
            for (int ct = 0; ct < 8; ++ct) { s += e[ct]; cs[ct] += e[ct]; }
            s += __shfl_xor(s, 1);
            s += __shfl_xor(s, 2);
            s += __shfl_xor(s, 4);
            s += __shfl_xor(s, 8);
            if (l16 == 0) {
                int o = (ns * 16 + jb) * LL + ib * 128 + arow + rt * 16 + quad * 4 + rg;
                Zpart[o] = s;
            }
        }

    // transpose: row sums for rows of jb (= cols here) over 128 rows of ib
    if (ib != jb) {
#pragma unroll
        for (int ct = 0; ct < 8; ++ct) {
            float s = cs[ct];
            s += __shfl_xor(s, 16);
            s += __shfl_xor(s, 32);
            cs[ct] = s;
        }
        __syncthreads();
        float* scs = (float*)AhU;                          // [128][5]
        if (quad == 0) {
#pragma unroll
            for (int ct = 0; ct < 8; ++ct) scs[(ct * 16 + l16) * 5 + wave] = cs[ct];
        }
        __syncthreads();
        if (tid < 128) {
            float S = scs[tid * 5] + scs[tid * 5 + 1] + scs[tid * 5 + 2] + scs[tid * 5 + 3];
            Zpart[(ns * 16 + ib) * LL + jb * 128 + tid] = S;
        }
    }
}

// ---------------------------------------------------------------------------
// Kernel 3: iZ[row] = 1 / sum of 16 per-tile partials
// ---------------------------------------------------------------------------
__global__ __launch_bounds__(256) void reduce_stats_kernel(
    const float* __restrict__ Zpart, float* __restrict__ iZfin)
{
    const int idx = blockIdx.x * 256 + threadIdx.x;   // ns*2048 + l
    const int ns = idx >> 11, l = idx & 2047;
    float Z = 0.f;
#pragma unroll
    for (int t = 0; t < 16; ++t) Z += Zpart[(ns * 16 + t) * LL + l];
    iZfin[idx] = 1.0f / Z;
}

// ---------------------------------------------------------------------------
// Kernel 4: recompute s (identical MFMA sequence), per-tile column partial
// sums of exp(s)*iZ_row for cols of BOTH blocks. Spart: [(ns*2048+m)*16+tile]
// ---------------------------------------------------------------------------
__global__ __launch_bounds__(256, 3) void colsum_kernel(
    const unsigned short* __restrict__ Ph, const unsigned short* __restrict__ Pl,
    const float* __restrict__ iZfin, float* __restrict__ Spart)
{
    __shared__ unsigned int AhU[2560], AlU[2560], BhU[2560], BlU[2560];
    int ib, jb;  pair_decode(blockIdx.x, ib, jb);
    const int ns = blockIdx.y;
    const int tid = threadIdx.x;
    const int lane = tid & 63, quad = lane >> 4, l16 = lane & 15, wave = tid >> 6;
    const int arow = wave * 32;

    float4v acc[2][8];
    mfma_core(Ph, Pl, ns, ib, jb, tid,
              (unsigned short*)AhU, (unsigned short*)AlU,
              (unsigned short*)BhU, (unsigned short*)BlU, acc);

    float wrow[2][4];
#pragma unroll
    for (int rt = 0; rt < 2; ++rt)
#pragma unroll
        for (int rg = 0; rg < 4; ++rg)
            wrow[rt][rg] = iZfin[ns * LL + ib * 128 + arow + rt * 16 + quad * 4 + rg];
    float wcol[8];
#pragma unroll
    for (int ct = 0; ct < 8; ++ct)
        wcol[ct] = iZfin[ns * LL + jb * 128 + ct * 16 + l16];

    float dsum[8];
#pragma unroll
    for (int ct = 0; ct < 8; ++ct) dsum[ct] = 0.f;

#pragma unroll
    for (int rt = 0; rt < 2; ++rt)
#pragma unroll
        for (int rg = 0; rg < 4; ++rg) {
            const int rl = arow + rt * 16 + quad * 4 + rg;
            float ts = 0.f;
#pragma unroll
            for (int ct = 0; ct < 8; ++ct) {
                float e = __expf(acc[rt][ct][rg] * SCALE);
                bool diag = (ib == jb) && (rl == ct * 16 + l16);
                dsum[ct] += diag ? 0.f : e * wrow[rt][rg];
                ts += e * wcol[ct];
            }
            if (ib != jb) {
                ts += __shfl_xor(ts, 1);
                ts += __shfl_xor(ts, 2);
                ts += __shfl_xor(ts, 4);
                ts += __shfl_xor(ts, 8);
                if (l16 == 0)
                    Spart[((size_t)ns * LL + ib * 128 + rl) * 16 + jb] = ts;
            }
        }

#pragma unroll
    for (int ct = 0; ct < 8; ++ct) {
        float s = dsum[ct];
        s += __shfl_xor(s, 16);
        s += __shfl_xor(s, 32);
        dsum[ct] = s;
    }
    __syncthreads();
    float* scr = (float*)AhU;                 // [128][5] cross-wave combine
    if (quad == 0) {
#pragma unroll
        for (int ct = 0; ct < 8; ++ct) scr[(ct * 16 + l16) * 5 + wave] = dsum[ct];
    }
    __syncthreads();
    if (tid < 128) {
        float t = scr[tid * 5] + scr[tid * 5 + 1] + scr[tid * 5 + 2] + scr[tid * 5 + 3];
        Spart[((size_t)ns * LL + jb * 128 + tid) * 16 + ib] = t;
    }
}

// ---------------------------------------------------------------------------
// Kernel 5: score = fp64 sum of 16 tile partials; exact bottom-k mask via
// rank counting: mask[i] = #{j: score_j < score_i} < 1024
// ---------------------------------------------------------------------------
__global__ __launch_bounds__(1024) void mask_kernel(
    const float* __restrict__ Spart, unsigned char* __restrict__ maskbuf)
{
    __shared__ double s[LL];
    const int ns = blockIdx.x;
    const int half = blockIdx.y;
    const int tid = threadIdx.x;
#pragma unroll
    for (int h = 0; h < 2; ++h) {
        int m = tid + h * 1024;
        const float* sp = Spart + ((size_t)ns * LL + m) * 16;
        double a = 0.0;
#pragma unroll
        for (int t = 0; t < 16; ++t) a += (double)sp[t];
        s[m] = a;
    }
    __syncthreads();
    const int i = half * 1024 + tid;
    const double si = s[i];
    int cnt = 0;
    for (int j = 0; j < LL; ++j) cnt += (s[j] < si) ? 1 : 0;
    maskbuf[ns * LL + i] = (cnt < 1024) ? 1 : 0;
}

// ---------------------------------------------------------------------------
// Kernel 6: blend, all fp32.
// ---------------------------------------------------------------------------
__global__ __launch_bounds__(256) void blend_kernel(
    const float* __restrict__ xt, const float* __restrict__ xf,
    const unsigned char* __restrict__ maskbuf, float* __restrict__ out)
{
    const int idx4 = blockIdx.x * 256 + threadIdx.x;
    const size_t q = (size_t)idx4 * 4;
    const int row = (int)(q >> 7);
    const float4 a = *(const float4*)(xt + q);
    const float4 b = *(const float4*)(xf + q);
    const int mt = maskbuf[row] & 1;
    const int mf = maskbuf[16384 + row] & 1;
    const bool ct = mt && !mf;
    const bool cf = mf && !mt;
    float4 av;
    av.x = 0.5f * (a.x + b.x);  av.y = 0.5f * (a.y + b.y);
    av.z = 0.5f * (a.z + b.z);  av.w = 0.5f * (a.w + b.w);
    float4 o0 = ct ? av : a;
    float4 o1 = cf ? av : b;
    *(float4*)(out + q)                   = o0;
    *(float4*)(out + (size_t)2097152 + q) = o1;
}

// ---------------------------------------------------------------------------
extern "C" void kernel_launch(void* const* d_in, const int* in_sizes, int n_in,
                              void* d_out, int out_size, void* d_ws, size_t ws_size,
                              hipStream_t stream)
{
    const float* xt = (const float*)d_in[0];
    const float* xf = (const float*)d_in[1];
    const float* W  = (const float*)d_in[2];
    const float* b  = (const float*)d_in[3];
    float* out = (float*)d_out;

    // d_out (16.8 MB) holds P split: Ph bf16 [0,8.39MB), Pl bf16 [8.39,16.8MB).
    // Both dead before blend overwrites d_out.
    unsigned short* Ph = (unsigned short*)d_out;
    unsigned short* Pl = Ph + (size_t)NS * SLAB;

    float* Zpart = (float*)d_ws;                       // 16*16*2048 = 524288 f
    float* iZfin = Zpart + 16 * 16 * LL;               // 32768 f
    float* Spart = iZfin + NS * LL;                    // 524288 f
    unsigned char* maskbuf = (unsigned char*)(Spart + (size_t)16 * LL * 16);
    // total ws ~4.4 MB

    proj_kernel<<<dim3(32, NS), 256, 0, stream>>>(xt, xf, W, b, Ph, Pl);
    stats_kernel<<<dim3(NPAIR, NS), 256, 0, stream>>>(Ph, Pl, Zpart);
    reduce_stats_kernel<<<128, 256, 0, stream>>>(Zpart, iZfin);
    colsum_kernel<<<dim3(NPAIR, NS), 256, 0, stream>>>(Ph, Pl, iZfin, Spart);
    mask_kernel<<<dim3(NS, 2), 1024, 0, stream>>>(Spart, maskbuf);
    blend_kernel<<<2048, 256, 0, stream>>>(xt, xf, maskbuf, out);
}